// Round 6
// baseline (295.383 us; speedup 1.0000x reference)
//
#include <hip/hip_runtime.h>
#include <stdint.h>

// LmHead: RMSNorm(8x4096) -> logits = h @ W^T (W: 32000x4096 f32) -> argmax per row.
// Memory-bound: W is 524 MB (> 256 MiB L3) -> pure HBM read stream, floor ~82us.
// R4 (126us): reg-dbuf h+W, counted vmcnt -- best so far. Residual defects:
//   (a) 2000 equal blocks vs ~768 resident -> 2.6 scheduling rounds, ~13% idle;
//   (b) h shares the vmcnt queue with W (in-order retirement chains them);
//   (c) h re-read from L2 costs 2x the W bytes in TCP/queue slots.
// R5 (168us): 2-deep W + full unroll + (256,3) cap -> spills. Reverted.
// R6: D sliced x4 (1024 cols). Block owns a slice: h-slice 32KB in LDS (read via
//   lgkmcnt, W is the ONLY vmcnt stream); 1000 persistent blocks (4x250, all
//   resident, exactly 8 groups/wave -> zero imbalance); R4's proven ping-pong.
//   Partials [4][8][32000] f32 summed+argmaxed by kernel C (deterministic).

#define D 4096
#define BATCH 8
#define VOCAB 32000
#define VT 4                  // vocab rows per wave-group
#define SLICES 4              // D split into 4 x 1024
#define BPS 250               // blocks per slice
#define NBLKB (SLICES * BPS)  // 1000 blocks, 4 waves each
#define GPW 8                 // groups per wave: 32000/(VT*1000) = 8 exactly
#define EPS 1e-6f

typedef unsigned long long u64;
typedef float f32x4 __attribute__((ext_vector_type(4)));

// ---------------- Kernel A: RMSNorm -> h in workspace ----------------
__global__ __launch_bounds__(256) void rmsnorm_k(const float* __restrict__ x,
                                                 const float* __restrict__ g,
                                                 float* __restrict__ h) {
    const int b = blockIdx.x;
    const int t = threadIdx.x;
    const int wave = t >> 6, lane = t & 63;
    const float* xr = x + b * D;

    f32x4 xv[4];
    float s = 0.f;
#pragma unroll
    for (int i = 0; i < 4; ++i) {
        xv[i] = *(const f32x4*)(xr + i * 1024 + t * 4);
        s += xv[i].x * xv[i].x + xv[i].y * xv[i].y + xv[i].z * xv[i].z + xv[i].w * xv[i].w;
    }
#pragma unroll
    for (int m = 1; m < 64; m <<= 1) s += __shfl_xor(s, m, 64);

    __shared__ float wsum[4];
    if (lane == 0) wsum[wave] = s;
    __syncthreads();
    const float tot = wsum[0] + wsum[1] + wsum[2] + wsum[3];
    const float rs = rsqrtf(tot * (1.f / (float)D) + EPS);

#pragma unroll
    for (int i = 0; i < 4; ++i) {
        const int d = i * 1024 + t * 4;
        const f32x4 gv = *(const f32x4*)(g + d);
        f32x4 o;
        o.x = xv[i].x * rs * gv.x;
        o.y = xv[i].y * rs * gv.y;
        o.z = xv[i].z * rs * gv.z;
        o.w = xv[i].w * rs * gv.w;
        *(f32x4*)(h + b * D + d) = o;
    }
}

// ---- Kernel B: slice-GEMV. h-slice in LDS (lgkmcnt), W sole vmcnt stream. ----
__global__ __launch_bounds__(256, 4) void gemv_slice_k(const float* __restrict__ W,
                                                       const float* __restrict__ h,
                                                       float* __restrict__ partial) {
    __shared__ float hs[BATCH][1024];   // 32 KB h-slice
    const int bid = blockIdx.x;
    const int s = bid & 3;              // slice id
    const int t = threadIdx.x;
    const int lane = t & 63, wave = t >> 6;
    const int scol = s * 1024;

    // stage h-slice -> LDS (8 rows x 1024 floats; one f32x4 per thread per row)
#pragma unroll
    for (int r = 0; r < BATCH; ++r)
        *(f32x4*)&hs[r][t * 4] = *(const f32x4*)(h + r * D + scol + t * 4);
    __syncthreads();

    const int wsub = (bid >> 2) * 4 + wave;       // [0, 1000) within this slice
    const int dl = lane * 4;

    float acc[32];
#pragma unroll
    for (int i = 0; i < 32; ++i) acc[i] = 0.f;

    f32x4 wA[VT], wB[VT];

#define LOADW(BUF, WGP, c)                                                      \
    {                                                                           \
        _Pragma("unroll")                                                       \
        for (int vi = 0; vi < VT; ++vi)                                         \
            BUF[vi] = __builtin_nontemporal_load(                               \
                (const f32x4*)((WGP) + (size_t)vi * D + (c) * 256));            \
    }

#define COMPUTE(BUF, c)                                                         \
    {                                                                           \
        _Pragma("unroll")                                                       \
        for (int b = 0; b < BATCH; ++b) {                                       \
            const f32x4 hv = *(const f32x4*)(&hs[b][(c) * 256 + dl]);           \
            _Pragma("unroll")                                                   \
            for (int vi = 0; vi < VT; ++vi)                                     \
                acc[b * VT + vi] += BUF[vi].x * hv.x + BUF[vi].y * hv.y +       \
                                    BUF[vi].z * hv.z + BUF[vi].w * hv.w;        \
        }                                                                       \
    }

// butterfly (static indices) -> lane l holds slice-partial for j=l&31
// (b=j>>2, vi=j&3); lanes<32 store; acc reset for next group.
#define FLUSH(g)                                                                \
    {                                                                           \
        _Pragma("unroll")                                                       \
        for (int st = 0; st < 5; ++st) {                                        \
            const int m = 1 << st;                                              \
            const bool bit = (lane & m) != 0;                                   \
            _Pragma("unroll")                                                   \
            for (int u = 0; u < (32 >> (st + 1)); ++u) {                        \
                const float a0 = acc[2 * u], a1 = acc[2 * u + 1];               \
                const float keep = bit ? a1 : a0;                               \
                const float send = bit ? a0 : a1;                               \
                acc[u] = keep + __shfl_xor(send, m, 64);                        \
            }                                                                   \
        }                                                                       \
        const float logit = acc[0] + __shfl_xor(acc[0], 32, 64);                \
        if (lane < 32) {                                                        \
            const int b_ = lane >> 2, vi_ = lane & 3;                           \
            const int v_ = (wsub * GPW + (g)) * VT + vi_;                       \
            partial[(size_t)(s * BATCH + b_) * VOCAB + v_] = logit;             \
        }                                                                       \
        _Pragma("unroll")                                                       \
        for (int i2 = 0; i2 < 32; ++i2) acc[i2] = 0.f;                          \
    }

    // wave's W base: rows [wsub*32, wsub*32+32), columns [scol, scol+1024)
    const float* Wg = W + (size_t)(wsub * 32) * D + scol + dl;

    // ping-pong, issue-order discipline (compute operands always oldest):
    LOADW(wA, Wg, 0)
#pragma unroll 1
    for (int g = 0; g < GPW - 1; ++g) {
        LOADW(wB, Wg, 1)
        COMPUTE(wA, 0)
        LOADW(wA, Wg, 2)
        COMPUTE(wB, 1)
        LOADW(wB, Wg, 3)
        COMPUTE(wA, 2)
        const float* Wn = Wg + (size_t)VT * D;
        LOADW(wA, Wn, 0)          // next group's first chunk: queue never drains
        COMPUTE(wB, 3)
        FLUSH(g)
        Wg = Wn;
    }
    // peeled last group (no next-group prefetch)
    LOADW(wB, Wg, 1)
    COMPUTE(wA, 0)
    LOADW(wA, Wg, 2)
    COMPUTE(wB, 1)
    LOADW(wB, Wg, 3)
    COMPUTE(wA, 2)
    COMPUTE(wB, 3)
    FLUSH(GPW - 1)
#undef LOADW
#undef COMPUTE
#undef FLUSH
}

// ------- Kernel C: sum 4 slice-partials per logit, argmax per batch row -------
__global__ __launch_bounds__(1024) void finalize_k(const float* __restrict__ partial,
                                                   int* __restrict__ out) {
    const int b = blockIdx.x;          // 8 blocks, one per batch row
    const int t = threadIdx.x;
    const int lane = t & 63, wave = t >> 6;
    const float* p0 = partial + (size_t)(0 * BATCH + b) * VOCAB;
    const float* p1 = partial + (size_t)(1 * BATCH + b) * VOCAB;
    const float* p2 = partial + (size_t)(2 * BATCH + b) * VOCAB;
    const float* p3 = partial + (size_t)(3 * BATCH + b) * VOCAB;

    u64 best = 0ull;
    for (int v = t; v < VOCAB; v += 1024) {
        const float sum = p0[v] + p1[v] + p2[v] + p3[v];
        const uint32_t fb = __float_as_uint(sum);
        const uint32_t key = (fb & 0x80000000u) ? ~fb : (fb | 0x80000000u);
        const u64 pk = ((u64)key << 32) | (uint32_t)(~(uint32_t)v);
        if (pk > best) best = pk;
    }
#pragma unroll
    for (int m = 1; m < 64; m <<= 1) {
        const u64 o = __shfl_xor(best, m, 64);
        if (o > best) best = o;
    }
    __shared__ u64 red[16];
    if (lane == 0) red[wave] = best;
    __syncthreads();
    if (t == 0) {
        u64 m = red[0];
#pragma unroll
        for (int i = 1; i < 16; ++i)
            if (red[i] > m) m = red[i];
        out[b] = (int)(~(uint32_t)m);
    }
}

extern "C" void kernel_launch(void* const* d_in, const int* in_sizes, int n_in,
                              void* d_out, int out_size, void* d_ws, size_t ws_size,
                              hipStream_t stream) {
    const float* x = (const float*)d_in[0]; // hidden_states [8,4096]
    const float* g = (const float*)d_in[1]; // norm_weight [4096]
    const float* W = (const float*)d_in[2]; // lm_head_weight [32000,4096]
    int* out = (int*)d_out;                 // [8] int32 token ids

    float* h = (float*)d_ws;                                          // 128 KB
    float* partial = (float*)((char*)d_ws + BATCH * D * sizeof(float)); // 4 MB

    rmsnorm_k<<<BATCH, 256, 0, stream>>>(x, g, h);
    gemv_slice_k<<<NBLKB, 256, 0, stream>>>(W, h, partial);
    finalize_k<<<BATCH, 1024, 0, stream>>>(partial, out);
}